// Round 7
// baseline (1280.556 us; speedup 1.0000x reference)
//
#include <hip/hip_runtime.h>
#include <hip/hip_bf16.h>
#include <math.h>

#define NT 1024
#define BSZ 128
#define TSTEPS 32
#define DIN 128
#define DHH 128
#define NSLOT 512
#define EPSF 1e-8f

// LDS: [0,131072) mem bf16[512][128] XOR-swizzled; then float scratch F[6872]
static constexpr int F_FLOATS = 6872;
static constexpr size_t LDS_BYTES = 131072 + F_FLOATS * sizeof(float);

__device__ __forceinline__ float us2f(unsigned short u) {
  union { unsigned short s; __hip_bfloat16 h; } c; c.s = u; return __bfloat162float(c.h);
}
__device__ __forceinline__ unsigned short f2us(float f) {
  union { unsigned short s; __hip_bfloat16 h; } c; c.h = __float2bfloat16(f); return c.s;
}
__device__ __forceinline__ unsigned pkbf(float a, float b) {   // packed cvt
  union { __hip_bfloat162 h2; unsigned u; } c;
  c.h2 = __float22bfloat162_rn(make_float2(a, b));
  return c.u;
}
__device__ __forceinline__ float sigmoid_(float x) { return 1.0f / (1.0f + __expf(-x)); }
__device__ __forceinline__ float softplus_(float x) {
  return fmaxf(x, 0.0f) + log1pf(__expf(-fabsf(x)));
}
__device__ __forceinline__ float tanh_(float x) {
  float e = __expf(-2.0f * fabsf(x));
  float t = (1.0f - e) / (1.0f + e);
  return copysignf(t, x);
}
__device__ __forceinline__ float waveSum(float v) {
#pragma unroll
  for (int m = 32; m >= 1; m >>= 1) v += __shfl_xor(v, m);
  return v;
}

// Pack Wr (128x134) + Ww (128x390) into padded WCat[128][528] f32 in d_ws:
// cols 0..133 = Wr, 134/135 = 0, 136..525 = Ww, 526/527 = 0. float4-aligned.
__global__ void prep_kernel(const float* __restrict__ Wr, const float* __restrict__ Ww,
                            float* __restrict__ wcat) {
  const int idx = blockIdx.x * 256 + threadIdx.x;
  if (idx >= 128 * 528) return;
  const int r = idx / 528, c = idx % 528;
  float v = 0.0f;
  if (c < 134) v = Wr[r * 134 + c];
  else if (c >= 136 && c < 526) v = Ww[r * 390 + (c - 136)];
  wcat[idx] = v;
}

// One block (1024 threads) per batch element; all 32 steps in-block.
// mem in LDS, rows XOR-swizzled: stored uint4 slot u = c ^ ((n>>2)&3).
__global__ __launch_bounds__(NT, 4)
void ntm_kernel(const float* __restrict__ x,
                const float* __restrict__ Wxh,
                const float* __restrict__ Whh,
                const float* __restrict__ Wrh,
                const float* __restrict__ bh,
                const float* __restrict__ Wout,
                const float* __restrict__ bout,
                const float* __restrict__ br,
                const float* __restrict__ bw,
                const float* __restrict__ WCat,
                float* __restrict__ out)
{
  extern __shared__ char smem[];
  uint4* memv = (uint4*)smem;              // bf16 mem, row n = 16 uint4 (swizzled)
  float* F = (float*)(smem + 131072);

  const int b = blockIdx.x;
  const int tid = threadIdx.x;
  const int g = tid >> 4, l = tid & 15;    // Phase-B mapping
  const int lane = tid & 63, wid = tid >> 6;

  float* U      = F + 0;      // 4224 multi-use: O-partials / eR,eW / B-red / Y-partials / H-partials(+2048)
  float* sWprev = F + 4224;   // 512  w_prev / becomes w_w
  float* sWr    = F + 4736;   // 512  w_r
  float* sWg    = F + 5248;   // 512  attention scratch
  float* sOr    = F + 5760;   // 144  (134 used)
  float* sOw    = F + 5904;   // 392  (390 used)
  float* sH     = F + 6296;   // 128
  float* sR     = F + 6424;   // 128
  float* sXt    = F + 6552;   // 128
  float* sP     = F + 6680;   // 64: [0..3] knorm, [16..31] esumR, [32..47] esumW, [48..63] psum
  uint4* krP    = (uint4*)(F + 6744);   // 16 uint4: k_r packed bf16
  uint4* kwP    = (uint4*)(F + 6808);   // 16 uint4: k_w packed bf16
  float* eR     = U + 0;      // 512 (during attention)
  float* eW     = U + 512;    // 512

  // ---- init ----
  {
    const unsigned short mb = f2us(1e-6f);
    const unsigned w32 = ((unsigned)mb << 16) | mb;
    const uint4 fv = make_uint4(w32, w32, w32, w32);
    for (int i = tid; i < NSLOT * DHH / 8; i += NT) memv[i] = fv;
  }
  for (int i = tid; i < NSLOT; i += NT) sWprev[i] = 1.0f / NSLOT;
  if (tid < DHH) { sH[tid] = 0.0f; sR[tid] = 0.0f; }
  if (tid < DIN) sXt[tid] = x[(size_t)b * TSTEPS * DIN + tid];
  __syncthreads();

  for (int t = 0; t < TSTEPS; ++t) {
    // ---- Phase H partials (float2, wave-uniform rows) + y-finalize(t-1) ----
    {
      if (t > 0 && tid < DIN) {
        float y = bout[tid];
#pragma unroll
        for (int q = 0; q < 16; ++q) y += U[q * 128 + tid];
        out[((size_t)b * TSTEPS + (t - 1)) * DIN + tid] = y;
      }
      const int q = tid & 63, s = tid >> 6;   // s == wid: wave-uniform rows
      const int j2 = q * 2, i0 = s * 24;
      float2 acc = make_float2(0.f, 0.f);
#pragma unroll 8
      for (int w = 0; w < 24; ++w) {
        const int i = i0 + w;
        float v; const float* Wp;
        if (i < 128)      { v = sXt[i];       Wp = Wxh + i * DHH; }
        else if (i < 256) { v = sH[i - 128];  Wp = Whh + (i - 128) * DHH; }
        else              { v = sR[i - 256];  Wp = Wrh + (i - 256) * DHH; }
        const float2 wv = *(const float2*)(Wp + j2);
        acc.x = fmaf(v, wv.x, acc.x);
        acc.y = fmaf(v, wv.y, acc.y);
      }
      *(float2*)(U + 2048 + s * 128 + j2) = acc;
      __syncthreads();
      if (tid < DHH) {
        float a2 = bh[tid];
#pragma unroll
        for (int q2 = 0; q2 < 16; ++q2) a2 += U[2048 + q2 * 128 + tid];
        sH[tid] = tanh_(a2);
      }
      __syncthreads();
    }

    // ---- Phase O: [o_r|o_w] = h @ WCat (padded f32, float4, branchless) ----
    {
      {
        const int q = tid & 127, s = tid >> 7;  // s uniform per 2 waves
        const int j4 = q * 4, i0 = s * 16;
        float4 acc = make_float4(0.f, 0.f, 0.f, 0.f);
#pragma unroll
        for (int i = i0; i < i0 + 16; ++i) {
          const float4 w = *(const float4*)(WCat + i * 528 + j4);
          const float v = sH[i];
          acc.x = fmaf(v, w.x, acc.x); acc.y = fmaf(v, w.y, acc.y);
          acc.z = fmaf(v, w.z, acc.z); acc.w = fmaf(v, w.w, acc.w);
        }
        *(float4*)(U + s * 528 + j4) = acc;
      }
      if (tid < 32) {                          // col-quads 128..131
        const int q = 128 + (tid & 3), s = tid >> 2;
        const int j4 = q * 4, i0 = s * 16;
        float4 acc = make_float4(0.f, 0.f, 0.f, 0.f);
#pragma unroll
        for (int i = i0; i < i0 + 16; ++i) {
          const float4 w = *(const float4*)(WCat + i * 528 + j4);
          const float v = sH[i];
          acc.x = fmaf(v, w.x, acc.x); acc.y = fmaf(v, w.y, acc.y);
          acc.z = fmaf(v, w.z, acc.z); acc.w = fmaf(v, w.w, acc.w);
        }
        *(float4*)(U + s * 528 + j4) = acc;
      }
      __syncthreads();
      if (tid < 528) {
        float v = 0.f;
#pragma unroll
        for (int s = 0; s < 8; ++s) v += U[s * 528 + tid];
        if (tid < 134) sOr[tid] = v + br[tid];
        else if (tid >= 136 && tid < 526) { const int cw = tid - 136; sOw[cw] = v + bw[cw]; }
      }
      __syncthreads();
      // knorm (waves 0-3) + e/a transforms (256..511) + key packing (512..543)
      {
        float v = 0.0f;
        if (tid < 128)      v = sOr[tid] * sOr[tid];
        else if (tid < 256) { const float z = sOw[tid - 128]; v = z * z; }
        v = waveSum(v);
        if (lane == 0) sP[wid] = v;
      }
      if (tid >= 256 && tid < 384)      { const int q = tid - 256; sOw[134 + q] = sigmoid_(sOw[134 + q]); }
      else if (tid >= 384 && tid < 512) { const int q = tid - 384; sOw[262 + q] = tanh_(sOw[262 + q]); }
      else if (tid >= 512 && tid < 544) {
        const int t2 = tid - 512;
        const int c = t2 & 15;
        const float* src = (t2 < 16) ? (sOr + c * 8) : (sOw + c * 8);
        union { uint4 v; unsigned short h[8]; } pk;
#pragma unroll
        for (int j = 0; j < 8; ++j) pk.h[j] = f2us(src[j]);
        if (t2 < 16) krP[c] = pk.v; else kwP[c] = pk.v;
      }
      __syncthreads();
    }
    // head scalars (redundant per-thread, LDS broadcast reads)
    const float kn_r = sqrtf(sP[0] + sP[1]);
    const float kn_w = sqrtf(sP[2] + sP[3]);
    float beta_r, g_r, sr0, sr1, sr2, gam_r;
    float beta_w, g_w, sw0, sw1, sw2, gam_w;
    {
      beta_r = softplus_(sOr[128]); g_r = sigmoid_(sOr[129]);
      float a0 = sOr[130], a1 = sOr[131], a2 = sOr[132];
      float mx = fmaxf(a0, fmaxf(a1, a2));
      float e0 = __expf(a0 - mx), e1 = __expf(a1 - mx), e2 = __expf(a2 - mx);
      float es = e0 + e1 + e2;
      sr0 = e0 / es; sr1 = e1 / es; sr2 = e2 / es;
      gam_r = 1.0f + softplus_(sOr[133]);

      beta_w = softplus_(sOw[128]); g_w = sigmoid_(sOw[129]);
      float b0 = sOw[130], b1 = sOw[131], b2 = sOw[132];
      float mw = fmaxf(b0, fmaxf(b1, b2));
      float f0 = __expf(b0 - mw), f1 = __expf(b1 - mw), f2 = __expf(b2 - mw);
      float fs = f0 + f1 + f2;
      sw0 = f0 / fs; sw1 = f1 / fs; sw2 = f2 / fs;
      gam_w = 1.0f + softplus_(sOw[133]);
    }

    // ---- Phase A + exp fused: thread owns half-row; e in-register ----
    {
      const int n = tid >> 1, hf = tid & 1;
      const int sw = (n >> 2) & 3;
      float dr = 0.f, dw = 0.f, ss = 0.f;
#pragma unroll
      for (int c = 0; c < 8; ++c) {
        const int cl = hf * 8 + c;
        union { uint4 v; unsigned short h[8]; } mv, kr, kw;
        mv.v = memv[n * 16 + (cl ^ sw)];
        kr.v = krP[cl];
        kw.v = kwP[cl];
#pragma unroll
        for (int j = 0; j < 8; ++j) {
          const float m = us2f(mv.h[j]);
          dr = fmaf(m, us2f(kr.h[j]), dr);
          dw = fmaf(m, us2f(kw.h[j]), dw);
          ss = fmaf(m, m, ss);
        }
      }
      dr += __shfl_xor(dr, 1);
      dw += __shfl_xor(dw, 1);
      ss += __shfl_xor(ss, 1);
      const float nr = sqrtf(ss);
      const float er = __expf(beta_r * dr / (nr * kn_r + EPSF));
      const float ew = __expf(beta_w * dw / (nr * kn_w + EPSF));
      if (hf == 0) { eR[n] = er; eW[n] = ew; }
      float s1 = waveSum(er) * 0.5f;   // each slot counted by both hf lanes
      float s2 = waveSum(ew) * 0.5f;
      if (lane == 0) { sP[16 + wid] = s1; sP[32 + wid] = s2; }
      __syncthreads();
    }

    // ---- Attention tail ----
    float invE_w;
    {
      float SR = 0.f, SW = 0.f;
#pragma unroll
      for (int q = 0; q < 16; ++q) { SR += sP[16 + q]; SW += sP[32 + q]; }
      const float invE_r = 1.0f / SR; invE_w = 1.0f / SW;
      if (tid < NSLOT) sWg[tid] = g_r * (eR[tid] * invE_r) + (1.0f - g_r) * sWprev[tid];
      __syncthreads();
    }
    float p1 = 0.0f;
    {
      if (tid < NSLOT) {
        const float wt = sr0 * sWg[(tid + 1) & 511] + sr1 * sWg[tid] + sr2 * sWg[(tid - 1) & 511];
        p1 = (wt > 0.0f) ? __expf(gam_r * __logf(wt)) : 0.0f;
      }
      float P = waveSum(p1);
      if (lane == 0) sP[48 + wid] = P;
      __syncthreads();
    }
    {
      float PS = 0.f;
#pragma unroll
      for (int q = 0; q < 16; ++q) PS += sP[48 + q];
      const float pinv = 1.0f / (PS + EPSF);
      if (tid < NSLOT) {
        const float wr = p1 * pinv;
        sWr[tid] = wr;
        sWg[tid] = g_w * (eW[tid] * invE_w) + (1.0f - g_w) * wr;
      }
      __syncthreads();
    }
    float p2 = 0.0f;
    {
      if (tid < NSLOT) {
        const float wt = sw0 * sWg[(tid + 1) & 511] + sw1 * sWg[tid] + sw2 * sWg[(tid - 1) & 511];
        p2 = (wt > 0.0f) ? __expf(gam_w * __logf(wt)) : 0.0f;
      }
      float P = waveSum(p2);
      if (lane == 0) sP[48 + wid] = P;
      __syncthreads();
    }
    {
      float PS = 0.f;
#pragma unroll
      for (int q = 0; q < 16; ++q) PS += sP[48 + q];
      const float pinv = 1.0f / (PS + EPSF);
      if (tid < NSLOT) sWprev[tid] = p2 * pinv;   // w_w
      __syncthreads();
    }

    // ---- Phase B: r = w_r·mem (old) fused with mem update by w_w ----
    {
      const int cl = l ^ ((g >> 2) & 3);   // logical chunk held by this lane
      float e8[8], a8[8], r8[8];
#pragma unroll
      for (int j = 0; j < 8; ++j) {
        e8[j] = sOw[134 + cl * 8 + j];
        a8[j] = sOw[262 + cl * 8 + j];
        r8[j] = 0.0f;
      }
#pragma unroll 2
      for (int it = 0; it < 8; ++it) {
        const int n = g + 64 * it;
        const float wrn = sWr[n];
        const float wwn = sWprev[n];
        union { uint4 v; unsigned short s[8]; } pk; pk.v = memv[n * 16 + l];
        float m[8];
#pragma unroll
        for (int j = 0; j < 8; ++j) m[j] = us2f(pk.s[j]);
#pragma unroll
        for (int j = 0; j < 8; ++j) {
          r8[j] = fmaf(wrn, m[j], r8[j]);
          const float d = fmaf(-e8[j], m[j], a8[j]);
          m[j] = fmaf(wwn, d, m[j]);
        }
        pk.v.x = pkbf(m[0], m[1]);
        pk.v.y = pkbf(m[2], m[3]);
        pk.v.z = pkbf(m[4], m[5]);
        pk.v.w = pkbf(m[6], m[7]);
        memv[n * 16 + l] = pk.v;
      }
#pragma unroll
      for (int j = 0; j < 8; ++j) {          // partners g^1,g^2 share chunk
        r8[j] += __shfl_xor(r8[j], 16);
        r8[j] += __shfl_xor(r8[j], 32);
      }
      if (lane < 16) {
#pragma unroll
        for (int j = 0; j < 8; ++j) U[wid * 128 + cl * 8 + j] = r8[j];
      }
      __syncthreads();
      if (tid < DHH) {
        float acc = 0.0f;
#pragma unroll
        for (int q = 0; q < 16; ++q) acc += U[q * 128 + tid];
        sR[tid] = acc;
      }
      __syncthreads();
    }

    // ---- Phase Y partials (float4, 512 threads) + x prefetch (896..1023) ----
    {
      if (tid >= 896 && t + 1 < TSTEPS) {
        const int i = tid - 896;
        sXt[i] = x[((size_t)b * TSTEPS + (t + 1)) * DIN + i];
      }
      if (tid < 512) {
        const int q = tid & 31, s = tid >> 5;
        const int j4 = q * 4, i0 = s * 16;
        float4 acc = make_float4(0.f, 0.f, 0.f, 0.f);
#pragma unroll
        for (int i = i0; i < i0 + 16; ++i) {
          const float v = (i < 128) ? sH[i] : sR[i - 128];
          const float4 w = *(const float4*)(Wout + i * DIN + j4);
          acc.x = fmaf(v, w.x, acc.x); acc.y = fmaf(v, w.y, acc.y);
          acc.z = fmaf(v, w.z, acc.z); acc.w = fmaf(v, w.w, acc.w);
        }
        *(float4*)(U + s * 128 + j4) = acc;
      }
      __syncthreads();
    }
  }

  // final y
  if (tid < DIN) {
    float y = bout[tid];
#pragma unroll
    for (int q = 0; q < 16; ++q) y += U[q * 128 + tid];
    out[((size_t)b * TSTEPS + (TSTEPS - 1)) * DIN + tid] = y;
  }
}

extern "C" void kernel_launch(void* const* d_in, const int* in_sizes, int n_in,
                              void* d_out, int out_size, void* d_ws, size_t ws_size,
                              hipStream_t stream) {
  (void)in_sizes; (void)n_in; (void)out_size; (void)ws_size;
  const float* Wr = (const float*)d_in[7];
  const float* Ww = (const float*)d_in[9];
  float* WCat = (float*)d_ws;   // 128*528 f32 = 270336 B

  prep_kernel<<<dim3((128 * 528 + 255) / 256), dim3(256), 0, stream>>>(Wr, Ww, WCat);

  hipFuncSetAttribute(reinterpret_cast<const void*>(ntm_kernel),
                      hipFuncAttributeMaxDynamicSharedMemorySize, (int)LDS_BYTES);
  ntm_kernel<<<dim3(BSZ), dim3(NT), LDS_BYTES, stream>>>(
      (const float*)d_in[0], (const float*)d_in[1], (const float*)d_in[2],
      (const float*)d_in[3], (const float*)d_in[4], (const float*)d_in[5],
      (const float*)d_in[6], (const float*)d_in[8], (const float*)d_in[10],
      WCat, (float*)d_out);
}

// Round 8
// 964.344 us; speedup vs baseline: 1.3279x; 1.3279x over previous
//
#include <hip/hip_runtime.h>
#include <hip/hip_bf16.h>
#include <math.h>

#define NT 1024
#define BSZ 128
#define TSTEPS 32
#define DIN 128
#define DHH 128
#define NSLOT 512
#define EPSF 1e-8f

// LDS: [0,131072) mem bf16[512][128] XOR-swizzled; then float scratch F[7160]
static constexpr int F_FLOATS = 7160;
static constexpr size_t LDS_BYTES = 131072 + F_FLOATS * sizeof(float);

__device__ __forceinline__ float bf_lo(unsigned u) {
  union { unsigned u; float f; } c; c.u = u << 16; return c.f;
}
__device__ __forceinline__ float bf_hi(unsigned u) {
  union { unsigned u; float f; } c; c.u = u & 0xffff0000u; return c.f;
}
__device__ __forceinline__ unsigned short f2us(float f) {
  union { unsigned short s; __hip_bfloat16 h; } c; c.h = __float2bfloat16(f); return c.s;
}
__device__ __forceinline__ unsigned pkbf(float a, float b) {
  union { __hip_bfloat162 h2; unsigned u; } c;
  c.h2 = __float22bfloat162_rn(make_float2(a, b));
  return c.u;
}
__device__ __forceinline__ float sigmoid_(float x) { return 1.0f / (1.0f + __expf(-x)); }
__device__ __forceinline__ float softplus_(float x) {
  return fmaxf(x, 0.0f) + log1pf(__expf(-fabsf(x)));
}
__device__ __forceinline__ float tanh_(float x) {
  float e = __expf(-2.0f * fabsf(x));
  float t = (1.0f - e) / (1.0f + e);
  return copysignf(t, x);
}
__device__ __forceinline__ float waveSum(float v) {
#pragma unroll
  for (int m = 32; m >= 1; m >>= 1) v += __shfl_xor(v, m);
  return v;
}

// One block (1024 threads) per batch element; all 32 steps in-block.
// mem in LDS, rows XOR-swizzled: stored uint4 slot u = c ^ ((n>>2)&3).
__global__ __launch_bounds__(NT, 4)
void ntm_kernel(const float* __restrict__ x,
                const float* __restrict__ Wxh,
                const float* __restrict__ Whh,
                const float* __restrict__ Wrh,
                const float* __restrict__ bh,
                const float* __restrict__ Wout,
                const float* __restrict__ bout,
                const float* __restrict__ Wr,
                const float* __restrict__ br,
                const float* __restrict__ Ww,
                const float* __restrict__ bw,
                float* __restrict__ out)
{
  extern __shared__ char smem[];
  uint4* memv = (uint4*)smem;              // bf16 mem, row n = 16 uint4 (swizzled)
  float* F = (float*)(smem + 131072);

  const int b = blockIdx.x;
  const int tid = threadIdx.x;
  const int g = tid >> 4, l = tid & 15;    // Phase-B mapping
  const int lane = tid & 63, wid = tid >> 6;

  // LDS float layout
  float* U      = F + 0;      // 2560 multi-use:
                              //   O: partials [0..2095]; H: partials [0..2047]
                              //   A/attn: eR [0..511], eW [512..1023]; beta: p2 -> [0..511]
                              //   B: partials [512..2559]
  float* yP     = F + 2560;   // 2048 Y partials (live across step boundary)
  float* sWprev = F + 4608;   // 512  w_prev (written in B as w_w)
  float* sWr    = F + 5120;   // 512  w_r
  float* sP1    = F + 5632;   // 512  p1 (attn); doubles as krP/kwP bf16 keys [0..127]
  float* sOr    = F + 6144;   // 144  o_r (134 used)
  float* sOw    = F + 6288;   // 392  o_w: [0..127] k_w, [128..133] scalars,
                              //      [136..263] e (16B-aligned), [264..391] a
  float* sH     = F + 6680;   // 128
  float* sR     = F + 6808;   // 128
  float* sXt    = F + 6936;   // 128
  float* sP     = F + 7064;   // 96: [0..3] knorm, [16..31] SR, [32..47] SW,
                              //     [48..63] P1, [64..79] P2, [80..91] head scalars
  uint4* krP    = (uint4*)(sP1 + 0);    // 16 uint4 packed k_r (dead before p1 written)
  uint4* kwP    = (uint4*)(sP1 + 64);   // 16 uint4 packed k_w
  float* eR     = U + 0;
  float* eW     = U + 512;

  // ---- init ----
  {
    const unsigned short mb = f2us(1e-6f);
    const unsigned w32 = ((unsigned)mb << 16) | mb;
    const uint4 fv = make_uint4(w32, w32, w32, w32);
    for (int i = tid; i < NSLOT * DHH / 8; i += NT) memv[i] = fv;
  }
  for (int i = tid; i < NSLOT; i += NT) sWprev[i] = 1.0f / NSLOT;
  if (tid < DHH) { sH[tid] = 0.0f; sR[tid] = 0.0f; }
  if (tid < DIN) sXt[tid] = x[(size_t)b * TSTEPS * DIN + tid];
  __syncthreads();

  for (int t = 0; t < TSTEPS; ++t) {
    // ==== Seg 1: H partials (float2, wave-uniform rows) + y-finalize(t-1) ====
    {
      if (t > 0 && tid < DIN) {
        float y = bout[tid];
#pragma unroll
        for (int q = 0; q < 16; ++q) y += yP[q * 128 + tid];
        out[((size_t)b * TSTEPS + (t - 1)) * DIN + tid] = y;
      }
      const int q = tid & 63, s = tid >> 6;   // s == wid: wave-uniform rows
      const int j2 = q * 2, i0 = s * 24;
      float2 acc = make_float2(0.f, 0.f);
#pragma unroll 8
      for (int w = 0; w < 24; ++w) {
        const int i = i0 + w;
        float v; const float* Wp;
        if (i < 128)      { v = sXt[i];       Wp = Wxh + i * DHH; }
        else if (i < 256) { v = sH[i - 128];  Wp = Whh + (i - 128) * DHH; }
        else              { v = sR[i - 256];  Wp = Wrh + (i - 256) * DHH; }
        const float2 wv = *(const float2*)(Wp + j2);
        acc.x = fmaf(v, wv.x, acc.x);
        acc.y = fmaf(v, wv.y, acc.y);
      }
      *(float2*)(U + s * 128 + j2) = acc;
      __syncthreads();
    }
    // ==== Seg 2: h = tanh(sum + bh) ====
    if (tid < DHH) {
      float a2 = bh[tid];
#pragma unroll
      for (int q2 = 0; q2 < 16; ++q2) a2 += U[q2 * 128 + tid];
      sH[tid] = tanh_(a2);
    }
    __syncthreads();

    // ==== Seg 3: O partials — 262 col-pairs x 4 row-quarters, float2 loads ====
    {
#pragma unroll
      for (int k = 0; k < 2; ++k) {
        const int s = tid + k * NT;
        if (s < 1048) {
          const int q = (s >= 786) ? 3 : (s >= 524) ? 2 : (s >= 262) ? 1 : 0;
          const int P = s - 262 * q;
          const float2* p;
          int strideF2;
          if (P < 67) { p = (const float2*)(Wr + 32 * q * 134 + 2 * P); strideF2 = 67; }
          else        { p = (const float2*)(Ww + 32 * q * 390 + 2 * (P - 67)); strideF2 = 195; }
          const int i0 = 32 * q;
          float2 acc = make_float2(0.f, 0.f);
#pragma unroll 8
          for (int w = 0; w < 32; ++w) {
            const float v = sH[i0 + w];
            const float2 wv = *p;
            acc.x = fmaf(v, wv.x, acc.x);
            acc.y = fmaf(v, wv.y, acc.y);
            p += strideF2;
          }
          *(float2*)(U + s * 2) = acc;   // U[c + 524q] with c = 2P+e
        }
      }
      __syncthreads();
    }
    // ==== Seg 4: O combine + bias ====
    if (tid < 524) {
      float v = 0.f;
#pragma unroll
      for (int q = 0; q < 4; ++q) v += U[tid + 524 * q];
      if (tid < 134) sOr[tid] = v + br[tid];
      else {
        const int cw = tid - 134;
        sOw[(cw < 134) ? cw : cw + 2] = v + bw[cw];   // e/a shifted +2 for alignment
      }
    }
    __syncthreads();
    // ==== Seg 5: knorm + e/a transforms + key packing + head scalars ====
    {
      if (wid < 4) {
        float v = (tid < 128) ? sOr[tid] * sOr[tid] : sOw[tid - 128] * sOw[tid - 128];
        v = waveSum(v);
        if (lane == 0) sP[wid] = v;
      } else if (tid >= 256 && tid < 384) {
        const int q = tid - 256; sOw[136 + q] = sigmoid_(sOw[136 + q]);
      } else if (tid >= 384 && tid < 512) {
        const int q = tid - 384; sOw[264 + q] = tanh_(sOw[264 + q]);
      } else if (tid >= 512 && tid < 544) {
        const int t2 = tid - 512;
        const int c = t2 & 15;
        const float* src = (t2 < 16) ? (sOr + c * 8) : (sOw + c * 8);
        union { uint4 v; unsigned short h[8]; } pk;
#pragma unroll
        for (int j = 0; j < 8; ++j) pk.h[j] = f2us(src[j]);
        if (t2 < 16) krP[c] = pk.v; else kwP[c] = pk.v;
      } else if (tid == 544) {       // read-head scalars
        sP[80] = softplus_(sOr[128]);
        sP[81] = sigmoid_(sOr[129]);
        float a0 = sOr[130], a1 = sOr[131], a2 = sOr[132];
        float mx = fmaxf(a0, fmaxf(a1, a2));
        float e0 = __expf(a0 - mx), e1 = __expf(a1 - mx), e2 = __expf(a2 - mx);
        float es = e0 + e1 + e2;
        sP[82] = e0 / es; sP[83] = e1 / es; sP[84] = e2 / es;
        sP[85] = 1.0f + softplus_(sOr[133]);
      } else if (tid == 545) {       // write-head scalars
        sP[86] = softplus_(sOw[128]);
        sP[87] = sigmoid_(sOw[129]);
        float a0 = sOw[130], a1 = sOw[131], a2 = sOw[132];
        float mx = fmaxf(a0, fmaxf(a1, a2));
        float e0 = __expf(a0 - mx), e1 = __expf(a1 - mx), e2 = __expf(a2 - mx);
        float es = e0 + e1 + e2;
        sP[88] = e0 / es; sP[89] = e1 / es; sP[90] = e2 / es;
        sP[91] = 1.0f + softplus_(sOw[133]);
      }
      __syncthreads();
    }

    // ==== Seg 6 (A): dots + norm + exp fused; publish eR/eW + SR/SW ====
    {
      const float kn_r = sqrtf(sP[0] + sP[1]);
      const float kn_w = sqrtf(sP[2] + sP[3]);
      const float beta_r = sP[80], beta_w = sP[86];
      const int n = tid >> 1, hf = tid & 1;
      const int sw = (n >> 2) & 3;
      float dr = 0.f, dw = 0.f, ss = 0.f;
#pragma unroll
      for (int c = 0; c < 8; ++c) {
        const int cl = hf * 8 + c;
        const uint4 mv = memv[n * 16 + (cl ^ sw)];
        const uint4 kr = krP[cl];
        const uint4 kw = kwP[cl];
        const unsigned mw_[4] = { mv.x, mv.y, mv.z, mv.w };
        const unsigned krw[4] = { kr.x, kr.y, kr.z, kr.w };
        const unsigned kww[4] = { kw.x, kw.y, kw.z, kw.w };
#pragma unroll
        for (int j = 0; j < 4; ++j) {
          const float m0 = bf_lo(mw_[j]), m1 = bf_hi(mw_[j]);
          dr = fmaf(m0, bf_lo(krw[j]), dr); dr = fmaf(m1, bf_hi(krw[j]), dr);
          dw = fmaf(m0, bf_lo(kww[j]), dw); dw = fmaf(m1, bf_hi(kww[j]), dw);
          ss = fmaf(m0, m0, ss);            ss = fmaf(m1, m1, ss);
        }
      }
      dr += __shfl_xor(dr, 1);
      dw += __shfl_xor(dw, 1);
      ss += __shfl_xor(ss, 1);
      const float nr = sqrtf(ss);
      const float er = __expf(beta_r * dr / (nr * kn_r + EPSF));
      const float ew = __expf(beta_w * dw / (nr * kn_w + EPSF));
      if (hf == 0) { eR[n] = er; eW[n] = ew; }
      float s1 = waveSum(er) * 0.5f;
      float s2 = waveSum(ew) * 0.5f;
      if (lane == 0) { sP[16 + wid] = s1; sP[32 + wid] = s2; }
      __syncthreads();
    }

    // ==== Seg 7 (alpha): p1 via on-the-fly w_g interpolation ====
    {
      float p1 = 0.0f;
      if (tid < NSLOT) {
        float SR = 0.f;
#pragma unroll
        for (int q = 0; q < 16; ++q) SR += sP[16 + q];
        const float invE = 1.0f / SR;
        const float gr = sP[81], omg = 1.0f - sP[81];
        const int im = (tid - 1) & 511, ip = (tid + 1) & 511;
        const float wgm = gr * (eR[im] * invE) + omg * sWprev[im];
        const float wg0 = gr * (eR[tid] * invE) + omg * sWprev[tid];
        const float wgp = gr * (eR[ip] * invE) + omg * sWprev[ip];
        const float wt = sP[82] * wgp + sP[83] * wg0 + sP[84] * wgm;
        p1 = (wt > 0.0f) ? __expf(sP[85] * __logf(wt)) : 0.0f;
      }
      float P = waveSum(p1);
      if (tid < NSLOT) sP1[tid] = p1;
      if (lane == 0) sP[48 + wid] = P;
      __syncthreads();
    }
    // ==== Seg 8 (beta): w_r, then p2 via on-the-fly w_g^w ====
    {
      float p2 = 0.0f;
      if (tid < NSLOT) {
        float PS = 0.f, SW = 0.f;
#pragma unroll
        for (int q = 0; q < 16; ++q) { PS += sP[48 + q]; SW += sP[32 + q]; }
        const float pinv1 = 1.0f / (PS + EPSF);
        const float invE = 1.0f / SW;
        const float gw = sP[87], omg = 1.0f - sP[87];
        const int im = (tid - 1) & 511, ip = (tid + 1) & 511;
        const float wgm = gw * (eW[im] * invE) + omg * (sP1[im] * pinv1);
        const float wg0 = gw * (eW[tid] * invE) + omg * (sP1[tid] * pinv1);
        const float wgp = gw * (eW[ip] * invE) + omg * (sP1[ip] * pinv1);
        sWr[tid] = sP1[tid] * pinv1;
        const float wt = sP[88] * wgp + sP[89] * wg0 + sP[90] * wgm;
        p2 = (wt > 0.0f) ? __expf(sP[91] * __logf(wt)) : 0.0f;
      }
      float P = waveSum(p2);
      if (tid < NSLOT) U[tid] = p2;       // raw p2 (eR region, dead)
      if (lane == 0) sP[64 + wid] = P;
      __syncthreads();
    }

    // ==== Seg 9 (B): w_w inline; r-sweep + mem update ====
    {
      float PS = 0.f;
#pragma unroll
      for (int q = 0; q < 16; ++q) PS += sP[64 + q];
      const float pinv2 = 1.0f / (PS + EPSF);
      if (tid < NSLOT) sWprev[tid] = U[tid] * pinv2;   // next step's w_prev

      const int cl = l ^ ((g >> 2) & 3);
      float4 e4a = *(const float4*)(sOw + 136 + cl * 8);
      float4 e4b = *(const float4*)(sOw + 140 + cl * 8);
      float4 a4a = *(const float4*)(sOw + 264 + cl * 8);
      float4 a4b = *(const float4*)(sOw + 268 + cl * 8);
      const float e8[8] = { e4a.x, e4a.y, e4a.z, e4a.w, e4b.x, e4b.y, e4b.z, e4b.w };
      const float a8[8] = { a4a.x, a4a.y, a4a.z, a4a.w, a4b.x, a4b.y, a4b.z, a4b.w };
      float r8[8] = { 0, 0, 0, 0, 0, 0, 0, 0 };
#pragma unroll 2
      for (int it = 0; it < 8; ++it) {
        const int n = g + 64 * it;
        const float wrn = sWr[n];
        const float wwn = U[n] * pinv2;
        uint4 pk = memv[n * 16 + l];
        const unsigned wds[4] = { pk.x, pk.y, pk.z, pk.w };
        float m[8];
#pragma unroll
        for (int j = 0; j < 4; ++j) { m[2 * j] = bf_lo(wds[j]); m[2 * j + 1] = bf_hi(wds[j]); }
#pragma unroll
        for (int j = 0; j < 8; ++j) {
          r8[j] = fmaf(wrn, m[j], r8[j]);
          const float d = fmaf(-e8[j], m[j], a8[j]);
          m[j] = fmaf(wwn, d, m[j]);
        }
        pk.x = pkbf(m[0], m[1]);
        pk.y = pkbf(m[2], m[3]);
        pk.z = pkbf(m[4], m[5]);
        pk.w = pkbf(m[6], m[7]);
        memv[n * 16 + l] = pk;
      }
#pragma unroll
      for (int j = 0; j < 8; ++j) {          // partners g^1,g^2 share chunk
        r8[j] += __shfl_xor(r8[j], 16);
        r8[j] += __shfl_xor(r8[j], 32);
      }
      if (lane < 16) {
        *(float4*)(U + 512 + wid * 128 + cl * 8)     = make_float4(r8[0], r8[1], r8[2], r8[3]);
        *(float4*)(U + 512 + wid * 128 + cl * 8 + 4) = make_float4(r8[4], r8[5], r8[6], r8[7]);
      }
      __syncthreads();
    }
    // ==== Seg 10: r combine ====
    if (tid < DHH) {
      float acc = 0.0f;
#pragma unroll
      for (int q = 0; q < 16; ++q) acc += U[512 + q * 128 + tid];
      sR[tid] = acc;
    }
    __syncthreads();

    // ==== Seg 11: Y partials (float4, 512 threads) + x prefetch ====
    {
      if (tid >= 896 && t + 1 < TSTEPS) {
        const int i = tid - 896;
        sXt[i] = x[((size_t)b * TSTEPS + (t + 1)) * DIN + i];
      }
      if (tid < 512) {
        const int q = tid & 31, s = tid >> 5;
        const int j4 = q * 4, i0 = s * 16;
        float4 acc = make_float4(0.f, 0.f, 0.f, 0.f);
#pragma unroll
        for (int i = i0; i < i0 + 16; ++i) {
          const float v = (i < 128) ? sH[i] : sR[i - 128];
          const float4 w = *(const float4*)(Wout + i * DIN + j4);
          acc.x = fmaf(v, w.x, acc.x); acc.y = fmaf(v, w.y, acc.y);
          acc.z = fmaf(v, w.z, acc.z); acc.w = fmaf(v, w.w, acc.w);
        }
        *(float4*)(yP + s * 128 + j4) = acc;
      }
      __syncthreads();
    }
  }

  // final y
  if (tid < DIN) {
    float y = bout[tid];
#pragma unroll
    for (int q = 0; q < 16; ++q) y += yP[q * 128 + tid];
    out[((size_t)b * TSTEPS + (TSTEPS - 1)) * DIN + tid] = y;
  }
}

extern "C" void kernel_launch(void* const* d_in, const int* in_sizes, int n_in,
                              void* d_out, int out_size, void* d_ws, size_t ws_size,
                              hipStream_t stream) {
  (void)in_sizes; (void)n_in; (void)out_size; (void)d_ws; (void)ws_size;
  hipFuncSetAttribute(reinterpret_cast<const void*>(ntm_kernel),
                      hipFuncAttributeMaxDynamicSharedMemorySize, (int)LDS_BYTES);
  ntm_kernel<<<dim3(BSZ), dim3(NT), LDS_BYTES, stream>>>(
      (const float*)d_in[0], (const float*)d_in[1], (const float*)d_in[2],
      (const float*)d_in[3], (const float*)d_in[4], (const float*)d_in[5],
      (const float*)d_in[6], (const float*)d_in[7], (const float*)d_in[8],
      (const float*)d_in[9], (const float*)d_in[10],
      (float*)d_out);
}